// Round 10
// baseline (69.994 us; speedup 1.0000x reference)
//
#include <hip/hip_runtime.h>
#include <hip/hip_bf16.h>
#include <stdint.h>

typedef __bf16 bf16x8 __attribute__((ext_vector_type(8)));
typedef float  f32x4  __attribute__((ext_vector_type(4)));

union U16x8 { bf16x8 v; unsigned short s[8]; uint4 q; };

// Schraudolph exp-in-bits: exp(x) ~= as_float((uint)(x*log2e*2^23 + (127-0.0437)*2^23))
// a is folded into the s-projection (k_proj), b into the MFMA accumulator C-input.
#define SCH_SCALE 12102203.0f      // log2(e) * 2^23
#define SCH_BIAS  1064986823.0f    // (127 - 0.043677) * 2^23

__device__ inline unsigned short f2bf(float f) {
  union { float f; unsigned int u; } x; x.f = f;
  unsigned int r = x.u + 0x7FFFu + ((x.u >> 16) & 1u);
  return (unsigned short)(r >> 16);
}
__device__ inline float bf2f(unsigned short u) {
  union { unsigned int u; float f; } x; x.u = ((unsigned int)u) << 16; return x.f;
}

// ---------------------------------------------------------------- K1: projections -> sT,fT,gT (bf16, [n][c]) + exact Sx partials
// sT is pre-scaled by SCH_SCALE so k_scores' MFMA emits a*F directly.
__global__ __launch_bounds__(256) void k_proj(
    const float* __restrict__ stu, const float* __restrict__ tea,
    const float* __restrict__ si_w, const float* __restrict__ fi_w, const float* __restrict__ gi_w,
    const float* __restrict__ si_b, const float* __restrict__ fi_b, const float* __restrict__ gi_b,
    unsigned short* __restrict__ sT, unsigned short* __restrict__ fT, unsigned short* __restrict__ gT,
    float* __restrict__ Sxp) {
  int bid = blockIdx.x;               // 256 = br_ba(8) * nt(32)
  int br_ba = bid & 7;
  int nt = bid >> 3;
  int br = br_ba >> 2, ba = br_ba & 3;
  const float* x = (br ? tea : stu) + (size_t)ba * 64 * 4096;
  int t = threadIdx.x;
  int wid = t >> 6, l = t & 63, g = l >> 4, lr = l & 15;
  int n0 = nt * 128 + wid * 32;

  U16x8 afr[2][2];
  float sx[2][8];
  #pragma unroll
  for (int kh = 0; kh < 2; ++kh)
    #pragma unroll
    for (int j = 0; j < 8; ++j) sx[kh][j] = 0.f;

  #pragma unroll
  for (int rf = 0; rf < 2; ++rf) {
    int n = n0 + rf * 16 + lr;
    #pragma unroll
    for (int kh = 0; kh < 2; ++kh) {
      #pragma unroll
      for (int j = 0; j < 8; ++j) {
        int c = kh * 32 + g * 8 + j;
        float v = x[(size_t)c * 4096 + n];
        afr[rf][kh].s[j] = f2bf(v);
        sx[kh][j] += v;
      }
    }
  }
  // exact spatial-sum partials: reduce over the 16 lr lanes (rows), collect per c
  #pragma unroll
  for (int kh = 0; kh < 2; ++kh)
    #pragma unroll
    for (int j = 0; j < 8; ++j) {
      float v = sx[kh][j];
      v += __shfl_xor(v, 1); v += __shfl_xor(v, 2);
      v += __shfl_xor(v, 4); v += __shfl_xor(v, 8);
      sx[kh][j] = v;
    }
  __shared__ float sxl[4][64];
  if (lr == 0) {
    #pragma unroll
    for (int kh = 0; kh < 2; ++kh)
      #pragma unroll
      for (int j = 0; j < 8; ++j)
        sxl[wid][kh * 32 + g * 8 + j] = sx[kh][j];
  }
  __syncthreads();
  if (t < 64)
    Sxp[bid * 64 + t] = (sxl[0][t] + sxl[1][t]) + (sxl[2][t] + sxl[3][t]);

  size_t obase = (size_t)br_ba * 4096 * 64;
  auto proj_one = [&](const float* w, const float* bias, float scale, unsigned short* op) {
    U16x8 bfr[4][2];
    #pragma unroll
    for (int cf = 0; cf < 4; ++cf) {
      int d = cf * 16 + lr;
      #pragma unroll
      for (int kh = 0; kh < 2; ++kh) {
        const float* wr = w + d * 64 + kh * 32 + g * 8;
        float4 w0 = *(const float4*)(wr);
        float4 w1 = *(const float4*)(wr + 4);
        bfr[cf][kh].s[0] = f2bf(w0.x * scale); bfr[cf][kh].s[1] = f2bf(w0.y * scale);
        bfr[cf][kh].s[2] = f2bf(w0.z * scale); bfr[cf][kh].s[3] = f2bf(w0.w * scale);
        bfr[cf][kh].s[4] = f2bf(w1.x * scale); bfr[cf][kh].s[5] = f2bf(w1.y * scale);
        bfr[cf][kh].s[6] = f2bf(w1.z * scale); bfr[cf][kh].s[7] = f2bf(w1.w * scale);
      }
    }
    f32x4 acc[2][4];
    #pragma unroll
    for (int rf = 0; rf < 2; ++rf)
      #pragma unroll
      for (int cf = 0; cf < 4; ++cf)
        acc[rf][cf] = (f32x4){0.f, 0.f, 0.f, 0.f};
    #pragma unroll
    for (int kh = 0; kh < 2; ++kh)
      #pragma unroll
      for (int rf = 0; rf < 2; ++rf)
        #pragma unroll
        for (int cf = 0; cf < 4; ++cf)
          acc[rf][cf] = __builtin_amdgcn_mfma_f32_16x16x32_bf16(
              afr[rf][kh].v, bfr[cf][kh].v, acc[rf][cf], 0, 0, 0);
    #pragma unroll
    for (int cf = 0; cf < 4; ++cf) {
      float bias_v = bias[cf * 16 + lr] * scale;
      #pragma unroll
      for (int rf = 0; rf < 2; ++rf) {
        #pragma unroll
        for (int r = 0; r < 4; ++r) {
          int n = n0 + rf * 16 + g * 4 + r;
          op[(size_t)n * 64 + cf * 16 + lr] = f2bf(acc[rf][cf][r] + bias_v);
        }
      }
    }
  };
  proj_one(si_w, si_b, SCH_SCALE, sT + obase);
  proj_one(fi_w, fi_b, 1.0f, fT + obase);
  proj_one(gi_w, gi_b, 1.0f, gT + obase);
}

// ---------------------------------------------------------------- K2: column exp-sums; minimal-instruction inner loop
// Block = 256 cols (4 waves x 64 distinct) x 256 rows (16 slices); all 4 waves
// read the SAME f-slice. Typed bf16x8 loads (no unions), bias passed as the
// MFMA C-input (no per-iter acc init), manual 2-slice body with named A/B
// prefetch regs, unroll 1. Epilogue = cvt_u32 + add per element.
__global__ __launch_bounds__(256) void k_scores(
    const unsigned short* __restrict__ sT, const unsigned short* __restrict__ fT,
    float* __restrict__ stats_w) {
  int bid = blockIdx.x;               // 2048 = br_ba(8) * cg(16) * rg(16)
  int br_ba = bid & 7;                // consecutive bids -> different XCDs
  int rest = bid >> 3;
  int cg = rest & 15;                 // 256-column group
  int rg = rest >> 4;                 // 256-row group
  int t = threadIdx.x;
  int wid = t >> 6, l = t & 63, g = l >> 4, lr = l & 15;

  // fragment index = row*8 + kh*4 + g  (bf16x8 granules of the [n][64] layout)
  const bf16x8* sv = (const bf16x8*)sT +
      (((size_t)br_ba * 4096 + cg * 256 + wid * 64 + lr) * 8 + g);
  const bf16x8* fv = (const bf16x8*)fT +
      (((size_t)br_ba * 4096 + rg * 256 + lr) * 8 + g);

  // this wave's 64 columns: nf stride = 16 cols = 128 granules; kh stride = 4
  bf16x8 b0k0 = sv[0],   b0k1 = sv[4];
  bf16x8 b1k0 = sv[128], b1k1 = sv[132];
  bf16x8 b2k0 = sv[256], b2k1 = sv[260];
  bf16x8 b3k0 = sv[384], b3k1 = sv[388];

  const f32x4 biasv = (f32x4){SCH_BIAS, SCH_BIAS, SCH_BIAS, SCH_BIAS};
  f32x4 S0 = (f32x4){0.f,0.f,0.f,0.f}, S1 = S0, S2 = S0, S3 = S0;

  bf16x8 fA0 = fv[0], fA1 = fv[4];
  bf16x8 fB0, fB1;

  #pragma unroll 1
  for (int k = 0; k < 16; k += 2) {
    // prefetch slice k+1
    fB0 = fv[(size_t)k * 128 + 128]; fB1 = fv[(size_t)k * 128 + 132];
    {
      f32x4 a0 = __builtin_amdgcn_mfma_f32_16x16x32_bf16(fA0, b0k0, biasv, 0,0,0);
      f32x4 a1 = __builtin_amdgcn_mfma_f32_16x16x32_bf16(fA0, b1k0, biasv, 0,0,0);
      f32x4 a2 = __builtin_amdgcn_mfma_f32_16x16x32_bf16(fA0, b2k0, biasv, 0,0,0);
      f32x4 a3 = __builtin_amdgcn_mfma_f32_16x16x32_bf16(fA0, b3k0, biasv, 0,0,0);
      a0 = __builtin_amdgcn_mfma_f32_16x16x32_bf16(fA1, b0k1, a0, 0,0,0);
      a1 = __builtin_amdgcn_mfma_f32_16x16x32_bf16(fA1, b1k1, a1, 0,0,0);
      a2 = __builtin_amdgcn_mfma_f32_16x16x32_bf16(fA1, b2k1, a2, 0,0,0);
      a3 = __builtin_amdgcn_mfma_f32_16x16x32_bf16(fA1, b3k1, a3, 0,0,0);
      #pragma unroll
      for (int r = 0; r < 4; ++r) {
        S0[r] += __uint_as_float((unsigned int)a0[r]);
        S1[r] += __uint_as_float((unsigned int)a1[r]);
        S2[r] += __uint_as_float((unsigned int)a2[r]);
        S3[r] += __uint_as_float((unsigned int)a3[r]);
      }
    }
    // prefetch slice k+2 (at k=14 this over-reads into gT: allocated, unused)
    fA0 = fv[(size_t)k * 128 + 256]; fA1 = fv[(size_t)k * 128 + 260];
    {
      f32x4 a0 = __builtin_amdgcn_mfma_f32_16x16x32_bf16(fB0, b0k0, biasv, 0,0,0);
      f32x4 a1 = __builtin_amdgcn_mfma_f32_16x16x32_bf16(fB0, b1k0, biasv, 0,0,0);
      f32x4 a2 = __builtin_amdgcn_mfma_f32_16x16x32_bf16(fB0, b2k0, biasv, 0,0,0);
      f32x4 a3 = __builtin_amdgcn_mfma_f32_16x16x32_bf16(fB0, b3k0, biasv, 0,0,0);
      a0 = __builtin_amdgcn_mfma_f32_16x16x32_bf16(fB1, b0k1, a0, 0,0,0);
      a1 = __builtin_amdgcn_mfma_f32_16x16x32_bf16(fB1, b1k1, a1, 0,0,0);
      a2 = __builtin_amdgcn_mfma_f32_16x16x32_bf16(fB1, b2k1, a2, 0,0,0);
      a3 = __builtin_amdgcn_mfma_f32_16x16x32_bf16(fB1, b3k1, a3, 0,0,0);
      #pragma unroll
      for (int r = 0; r < 4; ++r) {
        S0[r] += __uint_as_float((unsigned int)a0[r]);
        S1[r] += __uint_as_float((unsigned int)a1[r]);
        S2[r] += __uint_as_float((unsigned int)a2[r]);
        S3[r] += __uint_as_float((unsigned int)a3[r]);
      }
    }
  }

  // per-thread S*: 4-row subset (g-group) of this block's 256 rows, one column.
  // reduce across the 4 g-groups (shfl 16/32); waves own distinct columns.
  float w0 = (S0[0] + S0[1]) + (S0[2] + S0[3]);
  float w1 = (S1[0] + S1[1]) + (S1[2] + S1[3]);
  float w2 = (S2[0] + S2[1]) + (S2[2] + S2[3]);
  float w3 = (S3[0] + S3[1]) + (S3[2] + S3[3]);
  w0 += __shfl_xor(w0, 16); w0 += __shfl_xor(w0, 32);
  w1 += __shfl_xor(w1, 16); w1 += __shfl_xor(w1, 32);
  w2 += __shfl_xor(w2, 16); w2 += __shfl_xor(w2, 32);
  w3 += __shfl_xor(w3, 16); w3 += __shfl_xor(w3, 32);
  if (g == 0) {
    size_t cb = (size_t)br_ba * 4096 + cg * 256 + wid * 64 + lr;
    stats_w[(cb +  0) * 16 + rg] = w0;
    stats_w[(cb + 16) * 16 + rg] = w1;
    stats_w[(cb + 32) * 16 + rg] = w2;
    stats_w[(cb + 48) * 16 + rg] = w3;
  }
}

// ---------------------------------------------------------------- K4: row weights + gbar partials + Z partials
__global__ __launch_bounds__(256) void k_gbar(const unsigned short* __restrict__ gT,
                                              const float* __restrict__ stats_w,
                                              float* __restrict__ gbar_part,
                                              float* __restrict__ zpart) {
  int bid = blockIdx.x;               // 512 = br_ba(8) * seg(64)
  int br_ba = bid & 7;
  int seg = bid >> 3;
  int t = threadIdx.x;
  int n0 = seg * 64;

  __shared__ float wlds[64];
  if (t < 64) {
    const float4* p = (const float4*)(stats_w + ((size_t)br_ba * 4096 + n0 + t) * 16);
    float4 a = p[0], b = p[1], c = p[2], d = p[3];
    float w = (((a.x + a.y) + (a.z + a.w)) + ((b.x + b.y) + (b.z + b.w)))
            + (((c.x + c.y) + (c.z + c.w)) + ((d.x + d.y) + (d.z + d.w)));
    float zsum = w;
    zsum += __shfl_xor(zsum, 1);  zsum += __shfl_xor(zsum, 2);
    zsum += __shfl_xor(zsum, 4);  zsum += __shfl_xor(zsum, 8);
    zsum += __shfl_xor(zsum, 16); zsum += __shfl_xor(zsum, 32);
    if (t == 0) zpart[br_ba * 64 + seg] = zsum;
    wlds[t] = w;
  }
  __syncthreads();

  // gbar partial: sum_n w[n] * g[n][c]
  int c = t & 63, part = t >> 6;
  const unsigned short* gp = gT + ((size_t)br_ba * 4096 + n0) * 64;
  float acc = 0.f;
  #pragma unroll 4
  for (int r = 0; r < 16; ++r) {
    int k = part * 16 + r;
    acc += wlds[k] * bf2f(gp[(size_t)k * 64 + c]);
  }
  __shared__ float red[256];
  red[t] = acc; __syncthreads();
  if (t < 64)
    gbar_part[(size_t)(br_ba * 64 + seg) * 64 + c] =
        red[t] + red[t + 64] + red[t + 128] + red[t + 192];
}

// ---------------------------------------------------------------- K5: final loss
__global__ __launch_bounds__(256) void k_loss(const float* __restrict__ Sxp,
                                              const float* __restrict__ gbar_part,
                                              const float* __restrict__ zpart,
                                              const float* __restrict__ fsg_w,
                                              float* __restrict__ out) {
  int t = threadIdx.x;                // 256: ba = t>>6, d = t&63
  int ba = t >> 6, d = t & 63;
  __shared__ float zsh[8];
  if (t < 8) {
    float z = 0.f;
    for (int s2 = 0; s2 < 64; ++s2) z += zpart[t * 64 + s2];
    zsh[t] = z;
  }
  float gs = 0.f, gt_ = 0.f;
  for (int seg = 0; seg < 64; ++seg) {
    gs  += gbar_part[(size_t)((0 + ba) * 64 + seg) * 64 + d];
    gt_ += gbar_part[(size_t)((4 + ba) * 64 + seg) * 64 + d];
  }
  float sxs = 0.f, sxt = 0.f;
  for (int nt = 0; nt < 32; ++nt) {
    sxs += Sxp[(nt * 8 + 0 + ba) * 64 + d];
    sxt += Sxp[(nt * 8 + 4 + ba) * 64 + d];
  }
  __syncthreads();
  __shared__ float gdiff[4][64];
  gdiff[ba][d] = gs / zsh[ba] - gt_ / zsh[4 + ba];
  __syncthreads();
  float dot = 0.f;
  for (int c = 0; c < 64; ++c) dot += fsg_w[d * 64 + c] * gdiff[ba][c];
  float diff = ((sxs - sxt) + dot) * (1.0f / 4096.0f);
  __shared__ float red[256];
  red[t] = diff * diff; __syncthreads();
  for (int s = 128; s > 0; s >>= 1) { if (t < s) red[t] += red[t + s]; __syncthreads(); }
  if (t == 0) {
    float lnon = red[0];
    out[0] = 2e-5f * lnon;            // NON*R*lnon   (= non_loss * B)
    out[1] = 2e-5f * lnon * 0.25f;    // non_loss
  }
}

// ----------------------------------------------------------------
extern "C" void kernel_launch(void* const* d_in, const int* in_sizes, int n_in,
                              void* d_out, int out_size, void* d_ws, size_t ws_size,
                              hipStream_t stream) {
  const float* stu   = (const float*)d_in[0];
  const float* tea   = (const float*)d_in[1];
  const float* si_w  = (const float*)d_in[2];
  const float* si_b  = (const float*)d_in[3];
  const float* fi_w  = (const float*)d_in[4];
  const float* fi_b  = (const float*)d_in[5];
  const float* gi_w  = (const float*)d_in[6];
  const float* gi_b  = (const float*)d_in[7];
  const float* fsg_w = (const float*)d_in[8];
  // fsg_b (d_in[9]) cancels in the stu-tea difference.

  char* ws = (char*)d_ws;
  size_t off = 0;
  auto alloc = [&](size_t bytes) -> void* {
    void* p = ws + off;
    off = (off + bytes + 255) & ~(size_t)255;
    return p;
  };
  unsigned short* sT  = (unsigned short*)alloc((size_t)8 * 4096 * 64 * 2);
  unsigned short* fT  = (unsigned short*)alloc((size_t)8 * 4096 * 64 * 2);
  unsigned short* gT  = (unsigned short*)alloc((size_t)8 * 4096 * 64 * 2);
  float* stats_w      = (float*)alloc((size_t)8 * 4096 * 16 * 4);
  float* Sxp          = (float*)alloc((size_t)256 * 64 * 4);
  float* zpart        = (float*)alloc(512 * 4);
  float* gbar_part    = (float*)alloc((size_t)8 * 64 * 64 * 4);
  float* out          = (float*)d_out;

  k_proj<<<256, 256, 0, stream>>>(stu, tea, si_w, fi_w, gi_w, si_b, fi_b, gi_b, sT, fT, gT, Sxp);
  k_scores<<<2048, 256, 0, stream>>>(sT, fT, stats_w);
  k_gbar<<<512, 256, 0, stream>>>(gT, stats_w, gbar_part, zpart);
  k_loss<<<1, 256, 0, stream>>>(Sxp, gbar_part, zpart, fsg_w, out);
}

// Round 11
// 46.018 us; speedup vs baseline: 1.5210x; 1.5210x over previous
//
#include <hip/hip_runtime.h>
#include <hip/hip_bf16.h>
#include <stdint.h>

typedef __bf16 bf16x8 __attribute__((ext_vector_type(8)));
typedef float  f32x4  __attribute__((ext_vector_type(4)));

union U16x8 { bf16x8 v; unsigned short s[8]; uint4 q; };

// Schraudolph exp-in-bits: exp(x) ~= as_float((uint)(x*log2e*2^23 + (127-0.0437)*2^23))
// a is folded into the s-projection (k_proj), b into the MFMA accumulator C-input.
#define SCH_SCALE 12102203.0f      // log2(e) * 2^23
#define SCH_BIAS  1064986823.0f    // (127 - 0.043677) * 2^23

__device__ inline unsigned short f2bf(float f) {
  union { float f; unsigned int u; } x; x.f = f;
  unsigned int r = x.u + 0x7FFFu + ((x.u >> 16) & 1u);
  return (unsigned short)(r >> 16);
}
__device__ inline float bf2f(unsigned short u) {
  union { unsigned int u; float f; } x; x.u = ((unsigned int)u) << 16; return x.f;
}

// ---------------------------------------------------------------- K1: projections + exact Sx partials
// sT/fT written in MFMA FRAGMENT-MAJOR layout: ushort index within a br_ba =
//   ((slice(n>>4)*2 + kh(c>>5))*64 + lane((n&15) + 16*((c>>3)&3)))*8 + (c&7)
// so k_scores loads are lane-contiguous 1KB transactions. gT stays [n][c].
// sT is pre-scaled by SCH_SCALE so k_scores' MFMA emits a*F directly.
__global__ __launch_bounds__(256) void k_proj(
    const float* __restrict__ stu, const float* __restrict__ tea,
    const float* __restrict__ si_w, const float* __restrict__ fi_w, const float* __restrict__ gi_w,
    const float* __restrict__ si_b, const float* __restrict__ fi_b, const float* __restrict__ gi_b,
    unsigned short* __restrict__ sT, unsigned short* __restrict__ fT, unsigned short* __restrict__ gT,
    float* __restrict__ Sxp) {
  int bid = blockIdx.x;               // 256 = br_ba(8) * nt(32)
  int br_ba = bid & 7;
  int nt = bid >> 3;
  int br = br_ba >> 2, ba = br_ba & 3;
  const float* x = (br ? tea : stu) + (size_t)ba * 64 * 4096;
  int t = threadIdx.x;
  int wid = t >> 6, l = t & 63, g = l >> 4, lr = l & 15;
  int n0 = nt * 128 + wid * 32;

  U16x8 afr[2][2];
  float sx[2][8];
  #pragma unroll
  for (int kh = 0; kh < 2; ++kh)
    #pragma unroll
    for (int j = 0; j < 8; ++j) sx[kh][j] = 0.f;

  #pragma unroll
  for (int rf = 0; rf < 2; ++rf) {
    int n = n0 + rf * 16 + lr;
    #pragma unroll
    for (int kh = 0; kh < 2; ++kh) {
      #pragma unroll
      for (int j = 0; j < 8; ++j) {
        int c = kh * 32 + g * 8 + j;
        float v = x[(size_t)c * 4096 + n];
        afr[rf][kh].s[j] = f2bf(v);
        sx[kh][j] += v;
      }
    }
  }
  // exact spatial-sum partials: reduce over the 16 lr lanes (rows), collect per c
  #pragma unroll
  for (int kh = 0; kh < 2; ++kh)
    #pragma unroll
    for (int j = 0; j < 8; ++j) {
      float v = sx[kh][j];
      v += __shfl_xor(v, 1); v += __shfl_xor(v, 2);
      v += __shfl_xor(v, 4); v += __shfl_xor(v, 8);
      sx[kh][j] = v;
    }
  __shared__ float sxl[4][64];
  if (lr == 0) {
    #pragma unroll
    for (int kh = 0; kh < 2; ++kh)
      #pragma unroll
      for (int j = 0; j < 8; ++j)
        sxl[wid][kh * 32 + g * 8 + j] = sx[kh][j];
  }
  __syncthreads();
  if (t < 64)
    Sxp[bid * 64 + t] = (sxl[0][t] + sxl[1][t]) + (sxl[2][t] + sxl[3][t]);

  size_t obase = (size_t)br_ba * 4096 * 64;
  // frag=1 -> fragment-major (sT/fT), frag=0 -> row-major [n][64] (gT)
  auto proj_one = [&](const float* w, const float* bias, float scale,
                      unsigned short* op, int frag) {
    U16x8 bfr[4][2];
    #pragma unroll
    for (int cf = 0; cf < 4; ++cf) {
      int d = cf * 16 + lr;
      #pragma unroll
      for (int kh = 0; kh < 2; ++kh) {
        const float* wr = w + d * 64 + kh * 32 + g * 8;
        float4 w0 = *(const float4*)(wr);
        float4 w1 = *(const float4*)(wr + 4);
        bfr[cf][kh].s[0] = f2bf(w0.x * scale); bfr[cf][kh].s[1] = f2bf(w0.y * scale);
        bfr[cf][kh].s[2] = f2bf(w0.z * scale); bfr[cf][kh].s[3] = f2bf(w0.w * scale);
        bfr[cf][kh].s[4] = f2bf(w1.x * scale); bfr[cf][kh].s[5] = f2bf(w1.y * scale);
        bfr[cf][kh].s[6] = f2bf(w1.z * scale); bfr[cf][kh].s[7] = f2bf(w1.w * scale);
      }
    }
    f32x4 acc[2][4];
    #pragma unroll
    for (int rf = 0; rf < 2; ++rf)
      #pragma unroll
      for (int cf = 0; cf < 4; ++cf)
        acc[rf][cf] = (f32x4){0.f, 0.f, 0.f, 0.f};
    #pragma unroll
    for (int kh = 0; kh < 2; ++kh)
      #pragma unroll
      for (int rf = 0; rf < 2; ++rf)
        #pragma unroll
        for (int cf = 0; cf < 4; ++cf)
          acc[rf][cf] = __builtin_amdgcn_mfma_f32_16x16x32_bf16(
              afr[rf][kh].v, bfr[cf][kh].v, acc[rf][cf], 0, 0, 0);
    #pragma unroll
    for (int cf = 0; cf < 4; ++cf) {
      float bias_v = bias[cf * 16 + lr] * scale;
      int c = cf * 16 + lr;
      #pragma unroll
      for (int rf = 0; rf < 2; ++rf) {
        int sl = nt * 8 + wid * 2 + rf;          // n>>4
        #pragma unroll
        for (int r = 0; r < 4; ++r) {
          int n = n0 + rf * 16 + g * 4 + r;
          unsigned short val = f2bf(acc[rf][cf][r] + bias_v);
          if (frag) {
            size_t idx = ((size_t)(sl * 2 + (c >> 5)) * 64
                          + (g * 4 + r) + 16 * ((c >> 3) & 3)) * 8 + (c & 7);
            op[idx] = val;
          } else {
            op[(size_t)n * 64 + c] = val;
          }
        }
      }
    }
  };
  proj_one(si_w, si_b, SCH_SCALE, sT + obase, 1);
  proj_one(fi_w, fi_b, 1.0f, fT + obase, 1);
  proj_one(gi_w, gi_b, 1.0f, gT + obase, 0);
}

// ---------------------------------------------------------------- K2: column exp-sums; fully-coalesced fragment loads
// Block = 256 cols (4 waves x 64 distinct) x 1024 rows (32 slices); all 4
// waves read the SAME f-fragment addresses (L1 broadcast). Every load is
// lane-contiguous: granule (slice*2+kh)*64 + lane. Bias as MFMA C-input;
// epilogue = cvt_u32 (saturating) + add.
__global__ __launch_bounds__(256) void k_scores(
    const unsigned short* __restrict__ sT, const unsigned short* __restrict__ fT,
    float* __restrict__ stats_w) {
  int bid = blockIdx.x;               // 1024 = br_ba(8) * cg(16) * rg(8)
  int br_ba = bid & 7;                // consecutive bids -> different XCDs
  int rest = bid >> 3;
  int cg = rest & 15;                 // 256-column group
  int rg = rest >> 4;                 // 1024-row group
  int t = threadIdx.x;
  int wid = t >> 6, l = t & 63, g = l >> 4, lr = l & 15;

  const bf16x8* sfr = (const bf16x8*)sT + (size_t)br_ba * 32768;
  const bf16x8* ffr = (const bf16x8*)fT + (size_t)br_ba * 32768;

  // wave's 4 column-slices (64 cols): granule (sl*2+kh)*64 + l
  const bf16x8* sp = sfr + (size_t)(cg * 16 + wid * 4) * 128 + l;
  bf16x8 b0k0 = sp[0];   bf16x8 b0k1 = sp[64];
  bf16x8 b1k0 = sp[128]; bf16x8 b1k1 = sp[192];
  bf16x8 b2k0 = sp[256]; bf16x8 b2k1 = sp[320];
  bf16x8 b3k0 = sp[384]; bf16x8 b3k1 = sp[448];

  const bf16x8* fp = ffr + (size_t)(rg * 32) * 128 + l;

  const f32x4 biasv = (f32x4){SCH_BIAS, SCH_BIAS, SCH_BIAS, SCH_BIAS};
  f32x4 S0 = (f32x4){0.f,0.f,0.f,0.f}, S1 = S0, S2 = S0, S3 = S0;

  bf16x8 cur0 = fp[0], cur1 = fp[64];

  #pragma unroll 2
  for (int k = 0; k < 32; ++k) {
    bf16x8 nxt0, nxt1;
    if (k < 31) {
      nxt0 = fp[(size_t)(k + 1) * 128];
      nxt1 = fp[(size_t)(k + 1) * 128 + 64];
    }
    f32x4 a0 = __builtin_amdgcn_mfma_f32_16x16x32_bf16(cur0, b0k0, biasv, 0,0,0);
    f32x4 a1 = __builtin_amdgcn_mfma_f32_16x16x32_bf16(cur0, b1k0, biasv, 0,0,0);
    f32x4 a2 = __builtin_amdgcn_mfma_f32_16x16x32_bf16(cur0, b2k0, biasv, 0,0,0);
    f32x4 a3 = __builtin_amdgcn_mfma_f32_16x16x32_bf16(cur0, b3k0, biasv, 0,0,0);
    a0 = __builtin_amdgcn_mfma_f32_16x16x32_bf16(cur1, b0k1, a0, 0,0,0);
    a1 = __builtin_amdgcn_mfma_f32_16x16x32_bf16(cur1, b1k1, a1, 0,0,0);
    a2 = __builtin_amdgcn_mfma_f32_16x16x32_bf16(cur1, b2k1, a2, 0,0,0);
    a3 = __builtin_amdgcn_mfma_f32_16x16x32_bf16(cur1, b3k1, a3, 0,0,0);
    #pragma unroll
    for (int r = 0; r < 4; ++r) {
      S0[r] += __uint_as_float((unsigned int)a0[r]);   // v_cvt_u32_f32 saturates neg->0
      S1[r] += __uint_as_float((unsigned int)a1[r]);
      S2[r] += __uint_as_float((unsigned int)a2[r]);
      S3[r] += __uint_as_float((unsigned int)a3[r]);
    }
    cur0 = nxt0; cur1 = nxt1;
  }

  // per-thread S*: 4-row subset (g-group) of this block's 1024 rows, one column.
  float w0 = (S0[0] + S0[1]) + (S0[2] + S0[3]);
  float w1 = (S1[0] + S1[1]) + (S1[2] + S1[3]);
  float w2 = (S2[0] + S2[1]) + (S2[2] + S2[3]);
  float w3 = (S3[0] + S3[1]) + (S3[2] + S3[3]);
  w0 += __shfl_xor(w0, 16); w0 += __shfl_xor(w0, 32);
  w1 += __shfl_xor(w1, 16); w1 += __shfl_xor(w1, 32);
  w2 += __shfl_xor(w2, 16); w2 += __shfl_xor(w2, 32);
  w3 += __shfl_xor(w3, 16); w3 += __shfl_xor(w3, 32);
  if (g == 0) {
    size_t cb = (size_t)br_ba * 4096 + cg * 256 + wid * 64 + lr;
    stats_w[(cb +  0) * 8 + rg] = w0;
    stats_w[(cb + 16) * 8 + rg] = w1;
    stats_w[(cb + 32) * 8 + rg] = w2;
    stats_w[(cb + 48) * 8 + rg] = w3;
  }
}

// ---------------------------------------------------------------- K4: row weights + gbar partials + Z partials
__global__ __launch_bounds__(256) void k_gbar(const unsigned short* __restrict__ gT,
                                              const float* __restrict__ stats_w,
                                              float* __restrict__ gbar_part,
                                              float* __restrict__ zpart) {
  int bid = blockIdx.x;               // 512 = br_ba(8) * seg(64)
  int br_ba = bid & 7;
  int seg = bid >> 3;
  int t = threadIdx.x;
  int n0 = seg * 64;

  __shared__ float wlds[64];
  if (t < 64) {
    const float4* p = (const float4*)(stats_w + ((size_t)br_ba * 4096 + n0 + t) * 8);
    float4 a = p[0], b = p[1];
    float w = ((a.x + a.y) + (a.z + a.w)) + ((b.x + b.y) + (b.z + b.w));
    float zsum = w;
    zsum += __shfl_xor(zsum, 1);  zsum += __shfl_xor(zsum, 2);
    zsum += __shfl_xor(zsum, 4);  zsum += __shfl_xor(zsum, 8);
    zsum += __shfl_xor(zsum, 16); zsum += __shfl_xor(zsum, 32);
    if (t == 0) zpart[br_ba * 64 + seg] = zsum;
    wlds[t] = w;
  }
  __syncthreads();

  // gbar partial: sum_n w[n] * g[n][c]
  int c = t & 63, part = t >> 6;
  const unsigned short* gp = gT + ((size_t)br_ba * 4096 + n0) * 64;
  float acc = 0.f;
  #pragma unroll 4
  for (int r = 0; r < 16; ++r) {
    int k = part * 16 + r;
    acc += wlds[k] * bf2f(gp[(size_t)k * 64 + c]);
  }
  __shared__ float red[256];
  red[t] = acc; __syncthreads();
  if (t < 64)
    gbar_part[(size_t)(br_ba * 64 + seg) * 64 + c] =
        red[t] + red[t + 64] + red[t + 128] + red[t + 192];
}

// ---------------------------------------------------------------- K5: final loss
__global__ __launch_bounds__(256) void k_loss(const float* __restrict__ Sxp,
                                              const float* __restrict__ gbar_part,
                                              const float* __restrict__ zpart,
                                              const float* __restrict__ fsg_w,
                                              float* __restrict__ out) {
  int t = threadIdx.x;                // 256: ba = t>>6, d = t&63
  int ba = t >> 6, d = t & 63;
  __shared__ float zsh[8];
  if (t < 8) {
    float z = 0.f;
    for (int s2 = 0; s2 < 64; ++s2) z += zpart[t * 64 + s2];
    zsh[t] = z;
  }
  float gs = 0.f, gt_ = 0.f;
  for (int seg = 0; seg < 64; ++seg) {
    gs  += gbar_part[(size_t)((0 + ba) * 64 + seg) * 64 + d];
    gt_ += gbar_part[(size_t)((4 + ba) * 64 + seg) * 64 + d];
  }
  float sxs = 0.f, sxt = 0.f;
  for (int nt = 0; nt < 32; ++nt) {
    sxs += Sxp[(nt * 8 + 0 + ba) * 64 + d];
    sxt += Sxp[(nt * 8 + 4 + ba) * 64 + d];
  }
  __syncthreads();
  __shared__ float gdiff[4][64];
  gdiff[ba][d] = gs / zsh[ba] - gt_ / zsh[4 + ba];
  __syncthreads();
  float dot = 0.f;
  for (int c = 0; c < 64; ++c) dot += fsg_w[d * 64 + c] * gdiff[ba][c];
  float diff = ((sxs - sxt) + dot) * (1.0f / 4096.0f);
  __shared__ float red[256];
  red[t] = diff * diff; __syncthreads();
  for (int s = 128; s > 0; s >>= 1) { if (t < s) red[t] += red[t + s]; __syncthreads(); }
  if (t == 0) {
    float lnon = red[0];
    out[0] = 2e-5f * lnon;            // NON*R*lnon   (= non_loss * B)
    out[1] = 2e-5f * lnon * 0.25f;    // non_loss
  }
}

// ----------------------------------------------------------------
extern "C" void kernel_launch(void* const* d_in, const int* in_sizes, int n_in,
                              void* d_out, int out_size, void* d_ws, size_t ws_size,
                              hipStream_t stream) {
  const float* stu   = (const float*)d_in[0];
  const float* tea   = (const float*)d_in[1];
  const float* si_w  = (const float*)d_in[2];
  const float* si_b  = (const float*)d_in[3];
  const float* fi_w  = (const float*)d_in[4];
  const float* fi_b  = (const float*)d_in[5];
  const float* gi_w  = (const float*)d_in[6];
  const float* gi_b  = (const float*)d_in[7];
  const float* fsg_w = (const float*)d_in[8];
  // fsg_b (d_in[9]) cancels in the stu-tea difference.

  char* ws = (char*)d_ws;
  size_t off = 0;
  auto alloc = [&](size_t bytes) -> void* {
    void* p = ws + off;
    off = (off + bytes + 255) & ~(size_t)255;
    return p;
  };
  unsigned short* sT  = (unsigned short*)alloc((size_t)8 * 4096 * 64 * 2);
  unsigned short* fT  = (unsigned short*)alloc((size_t)8 * 4096 * 64 * 2);
  unsigned short* gT  = (unsigned short*)alloc((size_t)8 * 4096 * 64 * 2);
  float* stats_w      = (float*)alloc((size_t)8 * 4096 * 8 * 4);
  float* Sxp          = (float*)alloc((size_t)256 * 64 * 4);
  float* zpart        = (float*)alloc(512 * 4);
  float* gbar_part    = (float*)alloc((size_t)8 * 64 * 64 * 4);
  float* out          = (float*)d_out;

  k_proj<<<256, 256, 0, stream>>>(stu, tea, si_w, fi_w, gi_w, si_b, fi_b, gi_b, sT, fT, gT, Sxp);
  k_scores<<<1024, 256, 0, stream>>>(sT, fT, stats_w);
  k_gbar<<<512, 256, 0, stream>>>(gT, stats_w, gbar_part, zpart);
  k_loss<<<1, 256, 0, stream>>>(Sxp, gbar_part, zpart, fsg_w, out);
}